// Round 1
// baseline (867.123 us; speedup 1.0000x reference)
//
#include <hip/hip_runtime.h>
#include <hip/hip_bf16.h>
#include <cstdint>
#include <cstddef>

typedef __bf16 bf16_t;
typedef bf16_t bf16x8 __attribute__((ext_vector_type(8)));
typedef float  f32x4  __attribute__((ext_vector_type(4)));

// ---------------------------------------------------------------------------
// async global->LDS, 16B per lane (global_load_lds_dwordx4)
// ---------------------------------------------------------------------------
__device__ __forceinline__ void gl_lds16(const void* g, void* l) {
  __builtin_amdgcn_global_load_lds(
      (const __attribute__((address_space(1))) void*)g,
      (__attribute__((address_space(3))) void*)l, 16, 0, 0);
}

// ---------------------------------------------------------------------------
// Weight transpose + fp32->bf16: W[K][N] -> Wt[Npad][Kpad], zero-padded.
// block (32,8), grid (Kpad/32, Npad/32)
// ---------------------------------------------------------------------------
__global__ __launch_bounds__(256) void transpose_w(
    const float* __restrict__ W, bf16_t* __restrict__ Wt,
    int K, int N, int Kpad, int Npad)
{
  __shared__ float tile[32][33];
  const int tx = threadIdx.x, ty = threadIdx.y;
  const int k0 = blockIdx.x * 32, n0 = blockIdx.y * 32;
#pragma unroll
  for (int i = 0; i < 4; ++i) {
    int k = k0 + ty + i * 8, n = n0 + tx;
    tile[ty + i * 8][tx] = (k < K && n < N) ? W[(size_t)k * N + n] : 0.f;
  }
  __syncthreads();
#pragma unroll
  for (int i = 0; i < 4; ++i) {
    int n = n0 + ty + i * 8, k = k0 + tx;
    if (n < Npad && k < Kpad)
      Wt[(size_t)n * Kpad + k] = (bf16_t)tile[tx][ty + i * 8];
  }
}

// ---------------------------------------------------------------------------
// y (fp32 [12800][2520]) -> X0 (bf16 [12800][2560], zero-padded cols)
// one thread = 8 consecutive k. 2520 % 8 == 0, so vectors never straddle.
// ---------------------------------------------------------------------------
__global__ __launch_bounds__(256) void pack_x0(
    const float* __restrict__ y, bf16_t* __restrict__ X0)
{
  const int idx = blockIdx.x * 256 + threadIdx.x;   // 12800*320 total
  const int r = idx / 320, c = (idx % 320) * 8;
  bf16x8 v;
  if (c < 2520) {
    const float4 f0 = *(const float4*)(y + (size_t)r * 2520 + c);
    const float4 f1 = *(const float4*)(y + (size_t)r * 2520 + c + 4);
    v[0] = (bf16_t)f0.x; v[1] = (bf16_t)f0.y; v[2] = (bf16_t)f0.z; v[3] = (bf16_t)f0.w;
    v[4] = (bf16_t)f1.x; v[5] = (bf16_t)f1.y; v[6] = (bf16_t)f1.z; v[7] = (bf16_t)f1.w;
  } else {
#pragma unroll
    for (int j = 0; j < 8; ++j) v[j] = (bf16_t)0.f;
  }
  *(bf16x8*)(X0 + (size_t)r * 2560 + c) = v;
}

// ---------------------------------------------------------------------------
// GEMM: C[M][N] = A[M][K] @ Bt[N][K]^T + bias, optional ELU.
// 128x128 tile, BK=64, 4 waves, 16x16x32 bf16 MFMA (m97 structure).
// Cb: bf16 out (stride N) or null. Cf: fp32 out (stride Nlog) or null.
// Requires M%128==0, N%128==0, K%64==0. Stores/bias guarded by col<Nlog.
// ---------------------------------------------------------------------------
template<int ELU>
__global__ __launch_bounds__(256) void gemm_bt(
    const bf16_t* __restrict__ A, const bf16_t* __restrict__ Bt,
    const float* __restrict__ bias,
    bf16_t* __restrict__ Cb, float* __restrict__ Cf,
    int M, int N, int K, int Nlog)
{
  __shared__ __align__(16) bf16_t lA[128 * 64];
  __shared__ __align__(16) bf16_t lB[128 * 64];

  const int t    = threadIdx.x;
  const int w    = t >> 6, lane = t & 63;
  const int wm   = (w >> 1) * 64, wn = (w & 1) * 64;
  const int fr   = lane & 15, kg = lane >> 4;
  const int tm   = blockIdx.y * 128, tn = blockIdx.x * 128;
  const int r0   = t >> 3;          // staging row within 32-row chunk
  const int c0   = (t & 7) * 8;     // staging col (bf16 units)

  f32x4 acc[4][4];
#pragma unroll
  for (int i = 0; i < 4; ++i)
#pragma unroll
    for (int j = 0; j < 4; ++j) acc[i][j] = (f32x4){0.f, 0.f, 0.f, 0.f};

  for (int k0 = 0; k0 < K; k0 += 64) {
#pragma unroll
    for (int i = 0; i < 4; ++i) {
      const int r = i * 32 + r0;
      gl_lds16(A + (size_t)(tm + r) * K + k0 + c0, lA + r * 64 + c0);
    }
#pragma unroll
    for (int i = 0; i < 4; ++i) {
      const int r = i * 32 + r0;
      gl_lds16(Bt + (size_t)(tn + r) * K + k0 + c0, lB + r * 64 + c0);
    }
    asm volatile("s_waitcnt vmcnt(0)" ::: "memory");
    __syncthreads();
#pragma unroll
    for (int kc = 0; kc < 2; ++kc) {
      bf16x8 af[4], bfr[4];
#pragma unroll
      for (int i = 0; i < 4; ++i)
        af[i] = *(const bf16x8*)(lA + (wm + i * 16 + fr) * 64 + kc * 32 + kg * 8);
#pragma unroll
      for (int j = 0; j < 4; ++j)
        bfr[j] = *(const bf16x8*)(lB + (wn + j * 16 + fr) * 64 + kc * 32 + kg * 8);
#pragma unroll
      for (int i = 0; i < 4; ++i)
#pragma unroll
        for (int j = 0; j < 4; ++j)
          acc[i][j] = __builtin_amdgcn_mfma_f32_16x16x32_bf16(af[i], bfr[j], acc[i][j], 0, 0, 0);
    }
    __syncthreads();
  }

  // epilogue: C/D layout col = lane&15, row = (lane>>4)*4 + reg  [m89/m91]
#pragma unroll
  for (int i = 0; i < 4; ++i) {
    const int row0 = tm + wm + i * 16 + kg * 4;
#pragma unroll
    for (int j = 0; j < 4; ++j) {
      const int col = tn + wn + j * 16 + fr;
      const float bv = (col < Nlog) ? bias[col] : 0.f;
#pragma unroll
      for (int r = 0; r < 4; ++r) {
        float v = acc[i][j][r] + bv;
        if (ELU) v = (v > 0.f) ? v : expm1f(v);
        const int row = row0 + r;
        if (Cb) Cb[(size_t)row * N + col] = (bf16_t)v;
        if (Cf && col < Nlog) Cf[(size_t)row * Nlog + col] = v;
      }
    }
  }
}

// ---------------------------------------------------------------------------
// VQ: for each group (row,g) of 16 elems of ze, argmin_c ||z - e_c||^2 via
// d = 0.5*||e_c||^2 - <z, e_c>  (same argmin, first-index tie-break).
// Writes zq fp32 (d_out) and zq bf16 (decoder input). 4 groups/thread.
// ---------------------------------------------------------------------------
__global__ __launch_bounds__(256) void vq_kernel(
    const float* __restrict__ ze, const float* __restrict__ emb,
    float* __restrict__ zq, bf16_t* __restrict__ zqb)
{
  __shared__ float se[2048];
  __shared__ float sh[128];
  const int t = threadIdx.x;
  for (int i = t; i < 2048; i += 256) se[i] = emb[i];
  __syncthreads();
  if (t < 128) {
    float s = 0.f;
#pragma unroll
    for (int j = 0; j < 16; ++j) { float v = se[t * 16 + j]; s += v * v; }
    sh[t] = 0.5f * s;
  }
  __syncthreads();

  const size_t g0 = (size_t)blockIdx.x * 1024 + t;
  float z[4][16];
#pragma unroll
  for (int q = 0; q < 4; ++q) {
    const float4* p = (const float4*)(ze + (g0 + q * 256) * 16);
#pragma unroll
    for (int v = 0; v < 4; ++v) {
      float4 f = p[v];
      z[q][v * 4 + 0] = f.x; z[q][v * 4 + 1] = f.y;
      z[q][v * 4 + 2] = f.z; z[q][v * 4 + 3] = f.w;
    }
  }

  int   best[4] = {0, 0, 0, 0};
  float bd[4]   = {1e30f, 1e30f, 1e30f, 1e30f};
  for (int c = 0; c < 128; ++c) {
    float e[16];
    const float4* ep = (const float4*)(se + c * 16);
#pragma unroll
    for (int v = 0; v < 4; ++v) {
      float4 f = ep[v];
      e[v * 4 + 0] = f.x; e[v * 4 + 1] = f.y; e[v * 4 + 2] = f.z; e[v * 4 + 3] = f.w;
    }
    const float h = sh[c];
#pragma unroll
    for (int q = 0; q < 4; ++q) {
      float d = h;
#pragma unroll
      for (int j = 0; j < 16; ++j) d = fmaf(-z[q][j], e[j], d);
      if (d < bd[q]) { bd[q] = d; best[q] = c; }
    }
  }

#pragma unroll
  for (int q = 0; q < 4; ++q) {
    const float* e = se + best[q] * 16;
    float4* o = (float4*)(zq + (g0 + q * 256) * 16);
#pragma unroll
    for (int v = 0; v < 4; ++v) o[v] = ((const float4*)e)[v];
    bf16x8 b0, b1;
#pragma unroll
    for (int j = 0; j < 8; ++j) { b0[j] = (bf16_t)e[j]; b1[j] = (bf16_t)e[j + 8]; }
    *(bf16x8*)(zqb + (g0 + q * 256) * 16)     = b0;
    *(bf16x8*)(zqb + (g0 + q * 256) * 16 + 8) = b1;
  }
}

// ---------------------------------------------------------------------------
extern "C" void kernel_launch(void* const* d_in, const int* in_sizes, int n_in,
                              void* d_out, int out_size, void* d_ws, size_t ws_size,
                              hipStream_t stream)
{
  const float* y   = (const float*)d_in[0];
  const float* emb = (const float*)d_in[1];
  const float* eW1 = (const float*)d_in[2];
  const float* eb1 = (const float*)d_in[3];
  const float* eW2 = (const float*)d_in[4];
  const float* eb2 = (const float*)d_in[5];
  const float* eW3 = (const float*)d_in[6];
  const float* eb3 = (const float*)d_in[7];
  const float* dW1 = (const float*)d_in[8];
  const float* db1 = (const float*)d_in[9];
  const float* dW2 = (const float*)d_in[10];
  const float* db2 = (const float*)d_in[11];
  const float* dW3 = (const float*)d_in[12];
  const float* db3 = (const float*)d_in[13];

  float* out = (float*)d_out;               // [12800][2520]
  float* ze  = out + 32256000;              // [12800][2048]
  float* zq  = ze + 26214400;               // [12800][2048]

  uint8_t* ws = (uint8_t*)d_ws;
  size_t off = 0;
  auto alloc = [&](size_t bytes) -> void* {
    void* p = ws + off; off += (bytes + 255) & ~(size_t)255; return p;
  };
  bf16_t* X0  = (bf16_t*)alloc(12800ULL * 2560 * 2);
  bf16_t* W1t = (bf16_t*)alloc(1024ULL * 2560 * 2);
  bf16_t* W2t = (bf16_t*)alloc(1024ULL * 1024 * 2);
  bf16_t* W3t = (bf16_t*)alloc(2048ULL * 1024 * 2);
  bf16_t* V1t = (bf16_t*)alloc(1024ULL * 2048 * 2);
  bf16_t* V2t = (bf16_t*)alloc(1024ULL * 1024 * 2);
  bf16_t* V3t = (bf16_t*)alloc(2560ULL * 1024 * 2);
  bf16_t* H1  = (bf16_t*)alloc(12800ULL * 1024 * 2);
  bf16_t* H2  = (bf16_t*)alloc(12800ULL * 1024 * 2);
  bf16_t* ZQb = (bf16_t*)alloc(12800ULL * 2048 * 2);

  const dim3 tb(32, 8);
  transpose_w<<<dim3(80, 32), tb, 0, stream>>>(eW1, W1t, 2520, 1024, 2560, 1024);
  transpose_w<<<dim3(32, 32), tb, 0, stream>>>(eW2, W2t, 1024, 1024, 1024, 1024);
  transpose_w<<<dim3(32, 64), tb, 0, stream>>>(eW3, W3t, 1024, 2048, 1024, 2048);
  transpose_w<<<dim3(64, 32), tb, 0, stream>>>(dW1, V1t, 2048, 1024, 2048, 1024);
  transpose_w<<<dim3(32, 32), tb, 0, stream>>>(dW2, V2t, 1024, 1024, 1024, 1024);
  transpose_w<<<dim3(32, 80), tb, 0, stream>>>(dW3, V3t, 1024, 2520, 1024, 2560);

  pack_x0<<<16000, 256, 0, stream>>>(y, X0);

  // encoder
  gemm_bt<1><<<dim3(8, 100), 256, 0, stream>>>(X0, W1t, eb1, H1, nullptr, 12800, 1024, 2560, 1024);
  gemm_bt<1><<<dim3(8, 100), 256, 0, stream>>>(H1, W2t, eb2, H2, nullptr, 12800, 1024, 1024, 1024);
  gemm_bt<0><<<dim3(16, 100), 256, 0, stream>>>(H2, W3t, eb3, nullptr, ze, 12800, 2048, 1024, 2048);
  // vector quantize
  vq_kernel<<<1600, 256, 0, stream>>>(ze, emb, zq, ZQb);
  // decoder
  gemm_bt<1><<<dim3(8, 100), 256, 0, stream>>>(ZQb, V1t, db1, H1, nullptr, 12800, 1024, 2048, 1024);
  gemm_bt<1><<<dim3(8, 100), 256, 0, stream>>>(H1, V2t, db2, H2, nullptr, 12800, 1024, 1024, 1024);
  gemm_bt<0><<<dim3(20, 100), 256, 0, stream>>>(H2, V3t, db3, nullptr, out, 12800, 2560, 1024, 2520);
}

// Round 2
// 674.185 us; speedup vs baseline: 1.2862x; 1.2862x over previous
//
#include <hip/hip_runtime.h>
#include <hip/hip_bf16.h>
#include <cstdint>
#include <cstddef>

typedef __bf16 bf16_t;
typedef bf16_t bf16x8 __attribute__((ext_vector_type(8)));
typedef float  f32x4  __attribute__((ext_vector_type(4)));

// ---------------------------------------------------------------------------
// async global->LDS, 16B per lane (global_load_lds_dwordx4)
// ---------------------------------------------------------------------------
__device__ __forceinline__ void gl_lds16(const void* g, void* l) {
  __builtin_amdgcn_global_load_lds(
      (const __attribute__((address_space(1))) void*)g,
      (__attribute__((address_space(3))) void*)l, 16, 0, 0);
}

#define BAR()  __builtin_amdgcn_s_barrier()
#define LGK0() asm volatile("s_waitcnt lgkmcnt(0)" ::: "memory")

// ---------------------------------------------------------------------------
// Weight transpose + fp32->bf16: W[K][N] -> Wt[Npad][Kpad], zero-padded.
// ---------------------------------------------------------------------------
__global__ __launch_bounds__(256) void transpose_w(
    const float* __restrict__ W, bf16_t* __restrict__ Wt,
    int K, int N, int Kpad, int Npad)
{
  __shared__ float tile[32][33];
  const int tx = threadIdx.x, ty = threadIdx.y;
  const int k0 = blockIdx.x * 32, n0 = blockIdx.y * 32;
#pragma unroll
  for (int i = 0; i < 4; ++i) {
    int k = k0 + ty + i * 8, n = n0 + tx;
    tile[ty + i * 8][tx] = (k < K && n < N) ? W[(size_t)k * N + n] : 0.f;
  }
  __syncthreads();
#pragma unroll
  for (int i = 0; i < 4; ++i) {
    int n = n0 + ty + i * 8, k = k0 + tx;
    if (n < Npad && k < Kpad)
      Wt[(size_t)n * Kpad + k] = (bf16_t)tile[tx][ty + i * 8];
  }
}

// ---------------------------------------------------------------------------
// y (fp32 [12800][2520]) -> X0 (bf16 [12800][2560], zero-padded cols)
// ---------------------------------------------------------------------------
__global__ __launch_bounds__(256) void pack_x0(
    const float* __restrict__ y, bf16_t* __restrict__ X0)
{
  const int idx = blockIdx.x * 256 + threadIdx.x;   // 12800*320 total
  const int r = idx / 320, c = (idx % 320) * 8;
  bf16x8 v;
  if (c < 2520) {
    const float4 f0 = *(const float4*)(y + (size_t)r * 2520 + c);
    const float4 f1 = *(const float4*)(y + (size_t)r * 2520 + c + 4);
    v[0] = (bf16_t)f0.x; v[1] = (bf16_t)f0.y; v[2] = (bf16_t)f0.z; v[3] = (bf16_t)f0.w;
    v[4] = (bf16_t)f1.x; v[5] = (bf16_t)f1.y; v[6] = (bf16_t)f1.z; v[7] = (bf16_t)f1.w;
  } else {
#pragma unroll
    for (int j = 0; j < 8; ++j) v[j] = (bf16_t)0.f;
  }
  *(bf16x8*)(X0 + (size_t)r * 2560 + c) = v;
}

// ---------------------------------------------------------------------------
// swizzled LDS fragment read: half_ = base of a [128 rows][64 k] bf16 half-tile,
// st_16x32 swizzle byte ^= ((byte>>9)&1)<<5 (involution, 16B-granular).
// ---------------------------------------------------------------------------
__device__ __forceinline__ bf16x8 ldsfrag(const bf16_t* half_, int r, int kc, int kg) {
  int lin = (r << 7) + (kc << 6) + (kg << 4);   // bytes
  lin ^= ((lin >> 9) & 1) << 5;
  return *(const bf16x8*)((const char*)half_ + lin);
}

// ---------------------------------------------------------------------------
// 256x256x64 8-wave GEMM, 4 phases per K-tile, counted-vmcnt pipeline (T2+T3+T4+T5).
// C[M][N] = A[M][K] @ Bt[N][K]^T + bias, optional ELU.
// Cb: bf16 out (stride N) or null. Cf: fp32 out (stride Nlog) or null.
// Requires M%256==0, N%256==0, K%64==0 (K/64 >= 2).
// ---------------------------------------------------------------------------
template<int ELU>
__global__ __launch_bounds__(512, 2) void gemm256(
    const bf16_t* __restrict__ A, const bf16_t* __restrict__ Bt,
    const float* __restrict__ bias,
    bf16_t* __restrict__ Cb, float* __restrict__ Cf,
    int M, int N, int K, int Nlog)
{
  // [slot 0|1] x { A: 2 halves of [128][64] | B: 2 halves } = 128 KiB
  __shared__ __align__(16) bf16_t lds[65536];

  const int t  = threadIdx.x;
  const int w  = t >> 6, l = t & 63;
  const int fr = l & 15, kg = l >> 4;
  const int wm = (w >> 2) * 128, wn = (w & 3) * 64;   // 2M x 4N waves
  const int bro = (wn & 64);                          // B row offset within half

  // bijective XCD-aware remap of linear block id (m204)
  const int gx = gridDim.x;
  const int nwg = gx * (int)gridDim.y;
  int lin = blockIdx.y * gx + blockIdx.x;
  int q8 = nwg >> 3, r8 = nwg & 7, xcd = lin & 7, idx = lin >> 3;
  int swz = (xcd < r8 ? xcd * (q8 + 1) : r8 * (q8 + 1) + (xcd - r8) * q8) + idx;
  const int tn = (swz % gx) * 256;
  const int tm = (swz / gx) * 256;

  // staging constants: per half-tile, each thread issues 2 x 16B DMA.
  // LDS dest is linear (base + lane*16); global source col is pre-swizzled
  // so that swizzled ds_read recovers the logical element (rule #21).
  const int srow = w * 8 + (l >> 3);                        // 0..63
  const int sce  = ((l & 7) * 8) ^ (((l >> 5) & 1) << 4);   // source col, elems
  const int sdst = w * 512 + l * 8;                         // dest, elems (q=0)

  const int NT = K >> 6;

  f32x4 acc[8][4];
#pragma unroll
  for (int i = 0; i < 8; ++i)
#pragma unroll
    for (int j = 0; j < 4; ++j) acc[i][j] = (f32x4){0.f, 0.f, 0.f, 0.f};

  auto stage = [&](const bf16_t* gbase, bf16_t* lhalf) {
    gl_lds16(gbase + (size_t)srow * K + sce,        lhalf + sdst);
    gl_lds16(gbase + (size_t)(srow + 64) * K + sce, lhalf + 4096 + sdst);
  };

  // prologue: stage tile 0 into slot 0, drain once, barrier
  stage(A  + (size_t)tm * K,          lds);
  stage(A  + (size_t)(tm + 128) * K,  lds + 8192);
  stage(Bt + (size_t)tn * K,          lds + 16384);
  stage(Bt + (size_t)(tn + 128) * K,  lds + 16384 + 8192);
  asm volatile("s_waitcnt vmcnt(0)" ::: "memory");
  BAR();

  for (int kt = 0; kt < NT; ++kt) {
    const int s = kt & 1;
    const bf16_t* aH = lds + s * 32768 + (wm >> 7) * 8192;
    const bf16_t* bH = lds + s * 32768 + 16384 + (wn >> 7) * 8192;
    bf16_t* aNx = lds + (s ^ 1) * 32768;
    bf16_t* bNx = aNx + 16384;
    const bool pf = (kt + 1 < NT);
    const size_t kn = (size_t)(kt + 1) << 6;

    bf16x8 af[4][2], bf_[2][2];

    // ---------------- P1: A[0:4] x B[0:2] ----------------
#pragma unroll
    for (int mi = 0; mi < 4; ++mi)
#pragma unroll
      for (int kc = 0; kc < 2; ++kc)
        af[mi][kc] = ldsfrag(aH, mi * 16 + fr, kc, kg);
#pragma unroll
    for (int nj = 0; nj < 2; ++nj)
#pragma unroll
      for (int kc = 0; kc < 2; ++kc)
        bf_[nj][kc] = ldsfrag(bH, bro + nj * 16 + fr, kc, kg);
    if (pf) {
      stage(A + (size_t)tm * K + kn,         aNx);
      stage(A + (size_t)(tm + 128) * K + kn, aNx + 8192);
    }
    BAR(); LGK0();
    __builtin_amdgcn_s_setprio(1);
#pragma unroll
    for (int mi = 0; mi < 4; ++mi)
#pragma unroll
      for (int nj = 0; nj < 2; ++nj)
#pragma unroll
        for (int kc = 0; kc < 2; ++kc)
          acc[mi][nj] = __builtin_amdgcn_mfma_f32_16x16x32_bf16(af[mi][kc], bf_[nj][kc], acc[mi][nj], 0, 0, 0);
    __builtin_amdgcn_s_setprio(0);
    BAR();

    // ---------------- P2: A[0:4] x B[2:4] ----------------
#pragma unroll
    for (int nj = 0; nj < 2; ++nj)
#pragma unroll
      for (int kc = 0; kc < 2; ++kc)
        bf_[nj][kc] = ldsfrag(bH, bro + (nj + 2) * 16 + fr, kc, kg);
    if (pf) {
      stage(Bt + (size_t)tn * K + kn,         bNx);
      stage(Bt + (size_t)(tn + 128) * K + kn, bNx + 8192);
    }
    BAR(); LGK0();
    __builtin_amdgcn_s_setprio(1);
#pragma unroll
    for (int mi = 0; mi < 4; ++mi)
#pragma unroll
      for (int nj = 0; nj < 2; ++nj)
#pragma unroll
        for (int kc = 0; kc < 2; ++kc)
          acc[mi][nj + 2] = __builtin_amdgcn_mfma_f32_16x16x32_bf16(af[mi][kc], bf_[nj][kc], acc[mi][nj + 2], 0, 0, 0);
    __builtin_amdgcn_s_setprio(0);
    BAR();

    // ---------------- P3: A[4:8] x B[2:4] ----------------
#pragma unroll
    for (int mi = 0; mi < 4; ++mi)
#pragma unroll
      for (int kc = 0; kc < 2; ++kc)
        af[mi][kc] = ldsfrag(aH, (mi + 4) * 16 + fr, kc, kg);
    BAR(); LGK0();
    __builtin_amdgcn_s_setprio(1);
#pragma unroll
    for (int mi = 0; mi < 4; ++mi)
#pragma unroll
      for (int nj = 0; nj < 2; ++nj)
#pragma unroll
        for (int kc = 0; kc < 2; ++kc)
          acc[mi + 4][nj + 2] = __builtin_amdgcn_mfma_f32_16x16x32_bf16(af[mi][kc], bf_[nj][kc], acc[mi + 4][nj + 2], 0, 0, 0);
    __builtin_amdgcn_s_setprio(0);
    BAR();

    // ---------------- P4: A[4:8] x B[0:2] ----------------
#pragma unroll
    for (int nj = 0; nj < 2; ++nj)
#pragma unroll
      for (int kc = 0; kc < 2; ++kc)
        bf_[nj][kc] = ldsfrag(bH, bro + nj * 16 + fr, kc, kg);
    BAR(); LGK0();
    __builtin_amdgcn_s_setprio(1);
#pragma unroll
    for (int mi = 0; mi < 4; ++mi)
#pragma unroll
      for (int nj = 0; nj < 2; ++nj)
#pragma unroll
        for (int kc = 0; kc < 2; ++kc)
          acc[mi + 4][nj] = __builtin_amdgcn_mfma_f32_16x16x32_bf16(af[mi][kc], bf_[nj][kc], acc[mi + 4][nj], 0, 0, 0);
    __builtin_amdgcn_s_setprio(0);
    if (pf) asm volatile("s_waitcnt vmcnt(0)" ::: "memory");  // tile kt+1 resident
    BAR();
  }

  // epilogue: C/D layout col = lane&15, row = (lane>>4)*4 + reg
#pragma unroll
  for (int mi = 0; mi < 8; ++mi) {
    const int row0 = tm + wm + mi * 16 + kg * 4;
#pragma unroll
    for (int nj = 0; nj < 4; ++nj) {
      const int col = tn + wn + nj * 16 + fr;
      const float bv = (col < Nlog) ? bias[col] : 0.f;
#pragma unroll
      for (int r = 0; r < 4; ++r) {
        float v = acc[mi][nj][r] + bv;
        if (ELU) v = (v > 0.f) ? v : expm1f(v);
        const int row = row0 + r;
        if (Cb) Cb[(size_t)row * N + col] = (bf16_t)v;
        if (Cf && col < Nlog) Cf[(size_t)row * Nlog + col] = v;
      }
    }
  }
}

// ---------------------------------------------------------------------------
// VQ: argmin_c 0.5*||e_c||^2 - <z, e_c> per 16-elem group; write zq fp32 + bf16
// ---------------------------------------------------------------------------
__global__ __launch_bounds__(256) void vq_kernel(
    const float* __restrict__ ze, const float* __restrict__ emb,
    float* __restrict__ zq, bf16_t* __restrict__ zqb)
{
  __shared__ float se[2048];
  __shared__ float sh[128];
  const int t = threadIdx.x;
  for (int i = t; i < 2048; i += 256) se[i] = emb[i];
  __syncthreads();
  if (t < 128) {
    float s = 0.f;
#pragma unroll
    for (int j = 0; j < 16; ++j) { float v = se[t * 16 + j]; s += v * v; }
    sh[t] = 0.5f * s;
  }
  __syncthreads();

  const size_t g0 = (size_t)blockIdx.x * 1024 + t;
  float z[4][16];
#pragma unroll
  for (int q = 0; q < 4; ++q) {
    const float4* p = (const float4*)(ze + (g0 + q * 256) * 16);
#pragma unroll
    for (int v = 0; v < 4; ++v) {
      float4 f = p[v];
      z[q][v * 4 + 0] = f.x; z[q][v * 4 + 1] = f.y;
      z[q][v * 4 + 2] = f.z; z[q][v * 4 + 3] = f.w;
    }
  }

  int   best[4] = {0, 0, 0, 0};
  float bd[4]   = {1e30f, 1e30f, 1e30f, 1e30f};
  for (int c = 0; c < 128; ++c) {
    float e[16];
    const float4* ep = (const float4*)(se + c * 16);
#pragma unroll
    for (int v = 0; v < 4; ++v) {
      float4 f = ep[v];
      e[v * 4 + 0] = f.x; e[v * 4 + 1] = f.y; e[v * 4 + 2] = f.z; e[v * 4 + 3] = f.w;
    }
    const float h = sh[c];
#pragma unroll
    for (int q = 0; q < 4; ++q) {
      float d = h;
#pragma unroll
      for (int j = 0; j < 16; ++j) d = fmaf(-z[q][j], e[j], d);
      if (d < bd[q]) { bd[q] = d; best[q] = c; }
    }
  }

#pragma unroll
  for (int q = 0; q < 4; ++q) {
    const float* e = se + best[q] * 16;
    float4* o = (float4*)(zq + (g0 + q * 256) * 16);
#pragma unroll
    for (int v = 0; v < 4; ++v) o[v] = ((const float4*)e)[v];
    bf16x8 b0, b1;
#pragma unroll
    for (int j = 0; j < 8; ++j) { b0[j] = (bf16_t)e[j]; b1[j] = (bf16_t)e[j + 8]; }
    *(bf16x8*)(zqb + (g0 + q * 256) * 16)     = b0;
    *(bf16x8*)(zqb + (g0 + q * 256) * 16 + 8) = b1;
  }
}

// ---------------------------------------------------------------------------
extern "C" void kernel_launch(void* const* d_in, const int* in_sizes, int n_in,
                              void* d_out, int out_size, void* d_ws, size_t ws_size,
                              hipStream_t stream)
{
  const float* y   = (const float*)d_in[0];
  const float* emb = (const float*)d_in[1];
  const float* eW1 = (const float*)d_in[2];
  const float* eb1 = (const float*)d_in[3];
  const float* eW2 = (const float*)d_in[4];
  const float* eb2 = (const float*)d_in[5];
  const float* eW3 = (const float*)d_in[6];
  const float* eb3 = (const float*)d_in[7];
  const float* dW1 = (const float*)d_in[8];
  const float* db1 = (const float*)d_in[9];
  const float* dW2 = (const float*)d_in[10];
  const float* db2 = (const float*)d_in[11];
  const float* dW3 = (const float*)d_in[12];
  const float* db3 = (const float*)d_in[13];

  float* out = (float*)d_out;               // [12800][2520]
  float* ze  = out + 32256000;              // [12800][2048]
  float* zq  = ze + 26214400;               // [12800][2048]

  uint8_t* ws = (uint8_t*)d_ws;
  size_t off = 0;
  auto alloc = [&](size_t bytes) -> void* {
    void* p = ws + off; off += (bytes + 255) & ~(size_t)255; return p;
  };
  bf16_t* X0  = (bf16_t*)alloc(12800ULL * 2560 * 2);
  bf16_t* W1t = (bf16_t*)alloc(1024ULL * 2560 * 2);
  bf16_t* W2t = (bf16_t*)alloc(1024ULL * 1024 * 2);
  bf16_t* W3t = (bf16_t*)alloc(2048ULL * 1024 * 2);
  bf16_t* V1t = (bf16_t*)alloc(1024ULL * 2048 * 2);
  bf16_t* V2t = (bf16_t*)alloc(1024ULL * 1024 * 2);
  bf16_t* V3t = (bf16_t*)alloc(2560ULL * 1024 * 2);
  bf16_t* H1  = (bf16_t*)alloc(12800ULL * 1024 * 2);
  bf16_t* H2  = (bf16_t*)alloc(12800ULL * 1024 * 2);
  bf16_t* ZQb = (bf16_t*)alloc(12800ULL * 2048 * 2);

  const dim3 tb(32, 8);
  transpose_w<<<dim3(80, 32), tb, 0, stream>>>(eW1, W1t, 2520, 1024, 2560, 1024);
  transpose_w<<<dim3(32, 32), tb, 0, stream>>>(eW2, W2t, 1024, 1024, 1024, 1024);
  transpose_w<<<dim3(32, 64), tb, 0, stream>>>(eW3, W3t, 1024, 2048, 1024, 2048);
  transpose_w<<<dim3(64, 32), tb, 0, stream>>>(dW1, V1t, 2048, 1024, 2048, 1024);
  transpose_w<<<dim3(32, 32), tb, 0, stream>>>(dW2, V2t, 1024, 1024, 1024, 1024);
  transpose_w<<<dim3(32, 80), tb, 0, stream>>>(dW3, V3t, 1024, 2520, 1024, 2560);

  pack_x0<<<16000, 256, 0, stream>>>(y, X0);

  // encoder
  gemm256<1><<<dim3(4, 50), 512, 0, stream>>>(X0, W1t, eb1, H1, nullptr, 12800, 1024, 2560, 1024);
  gemm256<1><<<dim3(4, 50), 512, 0, stream>>>(H1, W2t, eb2, H2, nullptr, 12800, 1024, 1024, 1024);
  gemm256<0><<<dim3(8, 50), 512, 0, stream>>>(H2, W3t, eb3, nullptr, ze, 12800, 2048, 1024, 2048);
  // vector quantize
  vq_kernel<<<1600, 256, 0, stream>>>(ze, emb, zq, ZQb);
  // decoder
  gemm256<1><<<dim3(4, 50), 512, 0, stream>>>(ZQb, V1t, db1, H1, nullptr, 12800, 1024, 2048, 1024);
  gemm256<1><<<dim3(4, 50), 512, 0, stream>>>(H1, V2t, db2, H2, nullptr, 12800, 1024, 1024, 1024);
  gemm256<0><<<dim3(10, 50), 512, 0, stream>>>(H2, V3t, db3, nullptr, out, 12800, 2560, 1024, 2520);
}